// Round 1
// baseline (2917.273 us; speedup 1.0000x reference)
//
#include <hip/hip_runtime.h>

#define HID 256
#define N_FINE 262144
#define E_FINE 524288
#define N_COARSE 65536
#define E_COARSE 262144
#define NPITCH 260   // LDS row pitch for 256-wide activations (16B aligned, breaks 2^k strides)

static const size_t NODE_FLOATS = (size_t)N_COARSE * HID;   // 16,777,216
static const size_t EDGE_FLOATS = (size_t)E_COARSE * HID;   // 67,108,864
static const size_t IDX_OFF     = NODE_FLOATS + EDGE_FLOATS; // 83,886,080
#define IDX_N (2 * E_COARSE)                                 // 524,288

__device__ __forceinline__ float elu_f(float v) {
    return v > 0.0f ? v : (__expf(v) - 1.0f);
}

// ---------------- segment counts (int atomics) ----------------
__global__ __launch_bounds__(256) void counts_kernel(
    const int* __restrict__ f2ce, const int* __restrict__ f2ci,
    int* __restrict__ edgeCnt, int* __restrict__ nodeCnt)
{
    int i = blockIdx.x * 256 + threadIdx.x;   // grid covers E_FINE
    if (i < E_FINE) atomicAdd(&edgeCnt[f2ce[i]], 1);
    if (i < N_FINE) atomicAdd(&nodeCnt[f2ci[i]], 1);
}

// ---------------- exclusive scan of edgeCnt (262144 = 256 blocks x 1024) ----------------
__global__ __launch_bounds__(256) void scan1_kernel(
    const int* __restrict__ cnt, int* __restrict__ off, int* __restrict__ blockSums)
{
    __shared__ int s[256];
    int b = blockIdx.x;
    int t = threadIdx.x;
    const int4 v = *(const int4*)&cnt[b * 1024 + t * 4];
    int tsum = v.x + v.y + v.z + v.w;
    s[t] = tsum;
    __syncthreads();
    #pragma unroll
    for (int d = 1; d < 256; d <<= 1) {
        int val = (t >= d) ? s[t - d] : 0;
        __syncthreads();
        s[t] += val;
        __syncthreads();
    }
    int excl = s[t] - tsum;            // exclusive prefix within block
    if (t == 255) blockSums[b] = s[255];
    int4 o;
    o.x = excl;
    o.y = excl + v.x;
    o.z = o.y + v.y;
    o.w = o.z + v.z;
    *(int4*)&off[b * 1024 + t * 4] = o;
}

__global__ __launch_bounds__(256) void scan2_kernel(int* __restrict__ blockSums)
{
    __shared__ int s[256];
    int t = threadIdx.x;
    int v = blockSums[t];
    s[t] = v;
    __syncthreads();
    #pragma unroll
    for (int d = 1; d < 256; d <<= 1) {
        int val = (t >= d) ? s[t - d] : 0;
        __syncthreads();
        s[t] += val;
        __syncthreads();
    }
    blockSums[t] = s[t] - v;           // exclusive block offsets
}

__global__ __launch_bounds__(256) void scan3_kernel(
    int* __restrict__ off, const int* __restrict__ blockSums, int* __restrict__ cursor)
{
    int b = blockIdx.x;
    int t = threadIdx.x;
    int add = blockSums[b];
    int4 o = *(int4*)&off[b * 1024 + t * 4];
    o.x += add; o.y += add; o.z += add; o.w += add;
    *(int4*)&off[b * 1024 + t * 4] = o;
    *(int4*)&cursor[b * 1024 + t * 4] = o;   // cursor starts at offsets
}

// ---------------- bucket fine-edge ids by coarse edge ----------------
__global__ __launch_bounds__(256) void fill_kernel(
    const int* __restrict__ f2ce, int* __restrict__ cursor, int* __restrict__ bucket)
{
    int i = blockIdx.x * 256 + threadIdx.x;   // grid covers E_FINE
    int c = f2ce[i];
    int pos = atomicAdd(&cursor[c], 1);
    bucket[pos] = i;
}

// ---------------- edge mean via gather: one wave per coarse edge ----------------
__global__ __launch_bounds__(256) void edge_gather_kernel(
    const float* __restrict__ ea, const int* __restrict__ off,
    const int* __restrict__ cnt, const int* __restrict__ bucket,
    float* __restrict__ edgeSum)
{
    int t = threadIdx.x;
    int c = blockIdx.x * 4 + (t >> 6);
    int q = t & 63;
    int o = off[c];
    int n = cnt[c];
    float4 acc = make_float4(0.f, 0.f, 0.f, 0.f);
    int j = 0;
    for (; j + 1 < n; j += 2) {           // 2 rows in flight
        int fe0 = bucket[o + j];
        int fe1 = bucket[o + j + 1];
        const float4 v0 = *(const float4*)&ea[(size_t)fe0 * HID + (size_t)q * 4];
        const float4 v1 = *(const float4*)&ea[(size_t)fe1 * HID + (size_t)q * 4];
        acc.x += v0.x + v1.x; acc.y += v0.y + v1.y;
        acc.z += v0.z + v1.z; acc.w += v0.w + v1.w;
    }
    if (j < n) {
        int fe = bucket[o + j];
        const float4 v = *(const float4*)&ea[(size_t)fe * HID + (size_t)q * 4];
        acc.x += v.x; acc.y += v.y; acc.z += v.z; acc.w += v.w;
    }
    float s = (n > 0) ? 1.0f / (float)n : 0.0f;
    float4 r = make_float4(acc.x * s, acc.y * s, acc.z * s, acc.w * s);
    *(float4*)&edgeSum[(size_t)c * HID + (size_t)q * 4] = r;   // empty segment -> zeros
}

// ---------------- fallback: edge feature scatter-sum (old path) ----------------
__global__ __launch_bounds__(256) void edge_scatter_kernel(
    const float* __restrict__ ea, const int* __restrict__ f2ce,
    float* __restrict__ edgeSum)
{
    int t = threadIdx.x;
    size_t e = (size_t)blockIdx.x * 4 + (t >> 6);
    int q = t & 63;
    const float4 v = *(const float4*)&ea[e * HID + q * 4];
    int c = f2ce[e];
    float* p = edgeSum + (size_t)c * HID + (size_t)q * 4;
    unsafeAtomicAdd(p + 0, v.x);
    unsafeAtomicAdd(p + 1, v.y);
    unsafeAtomicAdd(p + 2, v.z);
    unsafeAtomicAdd(p + 3, v.w);
}

// ---------------- fused MLP: one 256x256 layer, W streamed through LDS ----------------
__device__ __forceinline__ void gemm_layer(
    const float* __restrict__ Wg,   // [256][256] row-major, global
    const float* sIn,               // LDS [16][NPITCH]
    float* sW,                      // LDS [16][256]
    float acc[4][4], int t, int mb, int n0)
{
    for (int kt = 0; kt < 16; ++kt) {
        __syncthreads();   // protect sW from previous tile's readers
        const float* wsrc = Wg + (size_t)kt * 16 * HID;
        #pragma unroll
        for (int r = 0; r < 4; ++r) {
            int id = r * 256 + t;                 // 0..1023 -> 16KB tile
            *(float4*)&sW[id * 4] = *(const float4*)&wsrc[id * 4];
        }
        __syncthreads();
        #pragma unroll
        for (int k4 = 0; k4 < 4; ++k4) {
            int kb = kt * 16 + k4 * 4;
            float4 w[4];
            #pragma unroll
            for (int kk = 0; kk < 4; ++kk)
                w[kk] = *(const float4*)&sW[(k4 * 4 + kk) * HID + n0];
            #pragma unroll
            for (int i = 0; i < 4; ++i) {
                float4 av = *(const float4*)&sIn[(mb + i) * NPITCH + kb];
                float am[4] = {av.x, av.y, av.z, av.w};
                #pragma unroll
                for (int kk = 0; kk < 4; ++kk) {
                    acc[i][0] = fmaf(am[kk], w[kk].x, acc[i][0]);
                    acc[i][1] = fmaf(am[kk], w[kk].y, acc[i][1]);
                    acc[i][2] = fmaf(am[kk], w[kk].z, acc[i][2]);
                    acc[i][3] = fmaf(am[kk], w[kk].w, acc[i][3]);
                }
            }
        }
    }
}

__global__ __launch_bounds__(256) void mlp_kernel(
    const float* __restrict__ x, const float* __restrict__ dist,
    const int* __restrict__ f2ci,
    const float* __restrict__ W1, const float* __restrict__ b1,
    const float* __restrict__ W2, const float* __restrict__ b2,
    const float* __restrict__ W3, const float* __restrict__ b3,
    float* __restrict__ nodeSum)
{
    __shared__ float s0[16 * NPITCH];   // x tile, then h2
    __shared__ float s1[16 * NPITCH];   // h1
    __shared__ float sW[16 * HID];      // streamed W tile

    const int t  = threadIdx.x;
    const int m0 = blockIdx.x * 16;
    const int n0 = (t & 63) * 4;        // output-column quad
    const int mb = (t >> 6) * 4;        // node quad

    // stage x tile (coalesced: each wave copies full 1KB rows)
    #pragma unroll
    for (int r = 0; r < 4; ++r) {
        int id = r * 256 + t;
        int m = id >> 6, k4 = id & 63;
        *(float4*)&s0[m * NPITCH + k4 * 4] =
            *(const float4*)&x[(size_t)(m0 + m) * HID + (size_t)k4 * 4];
    }

    float acc[4][4];

    // ---- layer 1: elu([x,d] @ W1 + b1); distance column folded into init ----
    {
        float4 bv = *(const float4*)&b1[n0];
        float4 wl = *(const float4*)&W1[(size_t)HID * HID + n0];  // W1 row 256
        #pragma unroll
        for (int i = 0; i < 4; ++i) {
            float d = dist[m0 + mb + i];
            acc[i][0] = fmaf(d, wl.x, bv.x);
            acc[i][1] = fmaf(d, wl.y, bv.y);
            acc[i][2] = fmaf(d, wl.z, bv.z);
            acc[i][3] = fmaf(d, wl.w, bv.w);
        }
    }
    gemm_layer(W1, s0, sW, acc, t, mb, n0);
    #pragma unroll
    for (int i = 0; i < 4; ++i) {
        float4 v = make_float4(elu_f(acc[i][0]), elu_f(acc[i][1]),
                               elu_f(acc[i][2]), elu_f(acc[i][3]));
        *(float4*)&s1[(mb + i) * NPITCH + n0] = v;
    }

    // ---- layer 2: elu(h1 @ W2 + b2) -> s0 (x no longer needed in LDS) ----
    {
        float4 bv = *(const float4*)&b2[n0];
        #pragma unroll
        for (int i = 0; i < 4; ++i) {
            acc[i][0] = bv.x; acc[i][1] = bv.y; acc[i][2] = bv.z; acc[i][3] = bv.w;
        }
    }
    gemm_layer(W2, s1, sW, acc, t, mb, n0);
    #pragma unroll
    for (int i = 0; i < 4; ++i) {
        float4 v = make_float4(elu_f(acc[i][0]), elu_f(acc[i][1]),
                               elu_f(acc[i][2]), elu_f(acc[i][3]));
        *(float4*)&s0[(mb + i) * NPITCH + n0] = v;
    }

    // ---- layer 3: h2 @ W3 + b3, + residual x (re-read), scatter to coarse ----
    {
        float4 bv = *(const float4*)&b3[n0];
        #pragma unroll
        for (int i = 0; i < 4; ++i) {
            acc[i][0] = bv.x; acc[i][1] = bv.y; acc[i][2] = bv.z; acc[i][3] = bv.w;
        }
    }
    gemm_layer(W3, s0, sW, acc, t, mb, n0);
    #pragma unroll
    for (int i = 0; i < 4; ++i) {
        size_t m = (size_t)(m0 + mb + i);
        float4 xr = *(const float4*)&x[m * HID + n0];
        int c = f2ci[m];
        float* p = nodeSum + (size_t)c * HID + n0;
        unsafeAtomicAdd(p + 0, acc[i][0] + xr.x);
        unsafeAtomicAdd(p + 1, acc[i][1] + xr.y);
        unsafeAtomicAdd(p + 2, acc[i][2] + xr.z);
        unsafeAtomicAdd(p + 3, acc[i][3] + xr.w);
    }
}

// ---------------- divide node sums by counts ----------------
__global__ __launch_bounds__(256) void normalize_nodes_kernel(
    float* __restrict__ out, const int* __restrict__ nodeCnt)
{
    size_t i4 = (size_t)blockIdx.x * 256 + threadIdx.x;  // grid covers NODE_FLOATS/4
    size_t f = i4 * 4;
    int cnt = nodeCnt[f >> 8];
    float s = 1.0f / (float)(cnt > 0 ? cnt : 1);
    float4 v = *(float4*)&out[f];
    v.x *= s; v.y *= s; v.z *= s; v.w *= s;
    *(float4*)&out[f] = v;
}

// ---------------- fallback: divide sums by counts (both regions) ----------------
__global__ __launch_bounds__(256) void normalize_kernel(
    float* __restrict__ out, const int* __restrict__ edgeCnt,
    const int* __restrict__ nodeCnt)
{
    size_t i4 = (size_t)blockIdx.x * 256 + threadIdx.x;
    size_t f = i4 * 4;
    int cnt;
    if (f < NODE_FLOATS) cnt = nodeCnt[f >> 8];
    else                 cnt = edgeCnt[(f - NODE_FLOATS) >> 8];
    float s = 1.0f / (float)(cnt > 0 ? cnt : 1);
    float4 v = *(float4*)&out[f];
    v.x *= s; v.y *= s; v.z *= s; v.w *= s;
    *(float4*)&out[f] = v;
}

// ---------------- coarse_edge_index passthrough (as float) ----------------
__global__ __launch_bounds__(256) void idx_copy_kernel(
    const int* __restrict__ cei, float* __restrict__ out)
{
    int i = blockIdx.x * 256 + threadIdx.x;   // grid covers IDX_N
    out[IDX_OFF + i] = (float)cei[i];
}

extern "C" void kernel_launch(void* const* d_in, const int* in_sizes, int n_in,
                              void* d_out, int out_size, void* d_ws, size_t ws_size,
                              hipStream_t stream)
{
    const float* x    = (const float*)d_in[0];
    const float* ea   = (const float*)d_in[1];
    const float* dist = (const float*)d_in[2];
    const int*   f2ci = (const int*)d_in[3];
    const int*   f2ce = (const int*)d_in[4];
    const int*   cei  = (const int*)d_in[5];
    const float* W1   = (const float*)d_in[6];
    const float* b1   = (const float*)d_in[7];
    const float* W2   = (const float*)d_in[8];
    const float* b2   = (const float*)d_in[9];
    const float* W3   = (const float*)d_in[10];
    const float* b3   = (const float*)d_in[11];

    float* out     = (float*)d_out;
    float* nodeSum = out;                  // [65536][256]
    float* edgeSum = out + NODE_FLOATS;    // [262144][256]

    // workspace layout (ints)
    int* edgeCnt   = (int*)d_ws;                    // 262144
    int* nodeCnt   = edgeCnt + E_COARSE;            // 65536
    int* edgeOff   = nodeCnt + N_COARSE;            // 262144
    int* cursor    = edgeOff + E_COARSE;            // 262144
    int* bucket    = cursor + E_COARSE;             // 524288
    int* blockSums = bucket + E_FINE;               // 256

    const size_t wsNeeded =
        (size_t)(E_COARSE + N_COARSE + E_COARSE + E_COARSE + E_FINE + 256) * sizeof(int);
    const bool gatherPath = (ws_size >= wsNeeded);

    if (gatherPath) {
        // zero only node sums + the two count arrays
        hipMemsetAsync(nodeSum, 0, NODE_FLOATS * sizeof(float), stream);
        hipMemsetAsync(d_ws, 0, (size_t)(E_COARSE + N_COARSE) * sizeof(int), stream);

        counts_kernel<<<E_FINE / 256, 256, 0, stream>>>(f2ce, f2ci, edgeCnt, nodeCnt);
        scan1_kernel<<<256, 256, 0, stream>>>(edgeCnt, edgeOff, blockSums);
        scan2_kernel<<<1, 256, 0, stream>>>(blockSums);
        scan3_kernel<<<256, 256, 0, stream>>>(edgeOff, blockSums, cursor);
        fill_kernel<<<E_FINE / 256, 256, 0, stream>>>(f2ce, cursor, bucket);
        edge_gather_kernel<<<E_COARSE / 4, 256, 0, stream>>>(ea, edgeOff, edgeCnt,
                                                             bucket, edgeSum);
        mlp_kernel<<<N_FINE / 16, 256, 0, stream>>>(x, dist, f2ci,
                                                    W1, b1, W2, b2, W3, b3, nodeSum);
        normalize_nodes_kernel<<<(unsigned)(NODE_FLOATS / 4 / 256), 256, 0, stream>>>(
            out, nodeCnt);
        idx_copy_kernel<<<IDX_N / 256, 256, 0, stream>>>(cei, out);
    } else {
        // fallback: previous verified atomic-scatter path
        hipMemsetAsync(d_out, 0, (NODE_FLOATS + EDGE_FLOATS) * sizeof(float), stream);
        hipMemsetAsync(d_ws, 0, (size_t)(E_COARSE + N_COARSE) * sizeof(int), stream);

        counts_kernel<<<E_FINE / 256, 256, 0, stream>>>(f2ce, f2ci, edgeCnt, nodeCnt);
        edge_scatter_kernel<<<E_FINE / 4, 256, 0, stream>>>(ea, f2ce, edgeSum);
        mlp_kernel<<<N_FINE / 16, 256, 0, stream>>>(x, dist, f2ci,
                                                    W1, b1, W2, b2, W3, b3, nodeSum);
        normalize_kernel<<<(unsigned)((NODE_FLOATS + EDGE_FLOATS) / 4 / 256), 256, 0, stream>>>(
            out, edgeCnt, nodeCnt);
        idx_copy_kernel<<<IDX_N / 256, 256, 0, stream>>>(cei, out);
    }
}

// Round 2
// 1744.130 us; speedup vs baseline: 1.6726x; 1.6726x over previous
//
#include <hip/hip_runtime.h>

#define HID 256
#define N_FINE 262144
#define E_FINE 524288
#define N_COARSE 65536
#define E_COARSE 262144
#define NPITCH 260   // LDS row pitch for 256-wide activations (fp32 fallback kernel)

static const size_t NODE_FLOATS = (size_t)N_COARSE * HID;   // 16,777,216
static const size_t EDGE_FLOATS = (size_t)E_COARSE * HID;   // 67,108,864
static const size_t IDX_OFF     = NODE_FLOATS + EDGE_FLOATS; // 83,886,080
#define IDX_N (2 * E_COARSE)                                 // 524,288

typedef __attribute__((ext_vector_type(8))) short bf16x8;   // 8 bf16 = 4 VGPRs
typedef __attribute__((ext_vector_type(4))) float f32x4;

__device__ __forceinline__ float elu_f(float v) {
    return v > 0.0f ? v : (__expf(v) - 1.0f);
}

__device__ __forceinline__ unsigned short bf16_rne(float f) {
    unsigned u = __float_as_uint(f);
    u += 0x7FFFu + ((u >> 16) & 1u);
    return (unsigned short)(u >> 16);
}
__device__ __forceinline__ float bf16_tof(unsigned short h) {
    return __uint_as_float((unsigned)h << 16);
}

// ---------------- segment counts (int atomics) ----------------
__global__ __launch_bounds__(256) void counts_kernel(
    const int* __restrict__ f2ce, const int* __restrict__ f2ci,
    int* __restrict__ edgeCnt, int* __restrict__ nodeCnt)
{
    int i = blockIdx.x * 256 + threadIdx.x;   // grid covers E_FINE
    if (i < E_FINE) atomicAdd(&edgeCnt[f2ce[i]], 1);
    if (i < N_FINE) atomicAdd(&nodeCnt[f2ci[i]], 1);
}

// ---------------- exclusive scan of edgeCnt (262144 = 256 blocks x 1024) ----------------
__global__ __launch_bounds__(256) void scan1_kernel(
    const int* __restrict__ cnt, int* __restrict__ off, int* __restrict__ blockSums)
{
    __shared__ int s[256];
    int b = blockIdx.x;
    int t = threadIdx.x;
    const int4 v = *(const int4*)&cnt[b * 1024 + t * 4];
    int tsum = v.x + v.y + v.z + v.w;
    s[t] = tsum;
    __syncthreads();
    #pragma unroll
    for (int d = 1; d < 256; d <<= 1) {
        int val = (t >= d) ? s[t - d] : 0;
        __syncthreads();
        s[t] += val;
        __syncthreads();
    }
    int excl = s[t] - tsum;
    if (t == 255) blockSums[b] = s[255];
    int4 o;
    o.x = excl;
    o.y = excl + v.x;
    o.z = o.y + v.y;
    o.w = o.z + v.z;
    *(int4*)&off[b * 1024 + t * 4] = o;
}

__global__ __launch_bounds__(256) void scan2_kernel(int* __restrict__ blockSums)
{
    __shared__ int s[256];
    int t = threadIdx.x;
    int v = blockSums[t];
    s[t] = v;
    __syncthreads();
    #pragma unroll
    for (int d = 1; d < 256; d <<= 1) {
        int val = (t >= d) ? s[t - d] : 0;
        __syncthreads();
        s[t] += val;
        __syncthreads();
    }
    blockSums[t] = s[t] - v;
}

__global__ __launch_bounds__(256) void scan3_kernel(
    int* __restrict__ off, const int* __restrict__ blockSums, int* __restrict__ cursor)
{
    int b = blockIdx.x;
    int t = threadIdx.x;
    int add = blockSums[b];
    int4 o = *(int4*)&off[b * 1024 + t * 4];
    o.x += add; o.y += add; o.z += add; o.w += add;
    *(int4*)&off[b * 1024 + t * 4] = o;
    *(int4*)&cursor[b * 1024 + t * 4] = o;
}

// ---------------- bucket fine-edge ids by coarse edge ----------------
__global__ __launch_bounds__(256) void fill_kernel(
    const int* __restrict__ f2ce, int* __restrict__ cursor, int* __restrict__ bucket)
{
    int i = blockIdx.x * 256 + threadIdx.x;
    int c = f2ce[i];
    int pos = atomicAdd(&cursor[c], 1);
    bucket[pos] = i;
}

// ---------------- edge mean via gather: one wave per coarse edge ----------------
__global__ __launch_bounds__(256) void edge_gather_kernel(
    const float* __restrict__ ea, const int* __restrict__ off,
    const int* __restrict__ cnt, const int* __restrict__ bucket,
    float* __restrict__ edgeSum)
{
    int t = threadIdx.x;
    int c = blockIdx.x * 4 + (t >> 6);
    int q = t & 63;
    int o = off[c];
    int n = cnt[c];
    float4 acc = make_float4(0.f, 0.f, 0.f, 0.f);
    int j = 0;
    for (; j + 1 < n; j += 2) {
        int fe0 = bucket[o + j];
        int fe1 = bucket[o + j + 1];
        const float4 v0 = *(const float4*)&ea[(size_t)fe0 * HID + (size_t)q * 4];
        const float4 v1 = *(const float4*)&ea[(size_t)fe1 * HID + (size_t)q * 4];
        acc.x += v0.x + v1.x; acc.y += v0.y + v1.y;
        acc.z += v0.z + v1.z; acc.w += v0.w + v1.w;
    }
    if (j < n) {
        int fe = bucket[o + j];
        const float4 v = *(const float4*)&ea[(size_t)fe * HID + (size_t)q * 4];
        acc.x += v.x; acc.y += v.y; acc.z += v.z; acc.w += v.w;
    }
    float s = (n > 0) ? 1.0f / (float)n : 0.0f;
    float4 r = make_float4(acc.x * s, acc.y * s, acc.z * s, acc.w * s);
    *(float4*)&edgeSum[(size_t)c * HID + (size_t)q * 4] = r;
}

// ---------------- fallback: edge feature scatter-sum (old path) ----------------
__global__ __launch_bounds__(256) void edge_scatter_kernel(
    const float* __restrict__ ea, const int* __restrict__ f2ce,
    float* __restrict__ edgeSum)
{
    int t = threadIdx.x;
    size_t e = (size_t)blockIdx.x * 4 + (t >> 6);
    int q = t & 63;
    const float4 v = *(const float4*)&ea[e * HID + q * 4];
    int c = f2ce[e];
    float* p = edgeSum + (size_t)c * HID + (size_t)q * 4;
    unsafeAtomicAdd(p + 0, v.x);
    unsafeAtomicAdd(p + 1, v.y);
    unsafeAtomicAdd(p + 2, v.z);
    unsafeAtomicAdd(p + 3, v.w);
}

// ================= MFMA MLP path =================
// W pre-split: WhT/WlT[layer][n][k] bf16, transposed so B-fragments are 16B contiguous.
__global__ __launch_bounds__(256) void wsplit_kernel(
    const float* __restrict__ W1, const float* __restrict__ W2,
    const float* __restrict__ W3, short* __restrict__ WhT, short* __restrict__ WlT)
{
    int i = blockIdx.x * 256 + threadIdx.x;   // 0 .. 3*65536-1
    int layer = i >> 16;
    int n = (i >> 8) & 255;
    int k = i & 255;
    const float* W = (layer == 0) ? W1 : ((layer == 1) ? W2 : W3);
    float v = W[(size_t)k * HID + n];
    unsigned short h = bf16_rne(v);
    unsigned short l = bf16_rne(v - bf16_tof(h));
    WhT[i] = (short)h;
    WlT[i] = (short)l;
}

// A-act LDS layout: [row][k] bf16, row pitch 256 shorts (512B = 32 granules of 16B),
// granule index XOR-swizzled with (row & 15) -> conflict-free stride-512B ds_read_b128.
__device__ __forceinline__ void mfma_layer(
    const short* sAh, const short* sAl,
    const short* __restrict__ WhTl, const short* __restrict__ WlTl,
    f32x4 acc[4][4], int l15, int l4, int wcol)
{
    #pragma unroll 2
    for (int ks = 0; ks < 8; ++ks) {
        bf16x8 ah[4], al[4], bh[4], bl[4];
        #pragma unroll
        for (int m = 0; m < 4; ++m) {
            int row = m * 16 + l15;
            int gx = (ks * 4 + l4) ^ l15;
            int si = row * 256 + gx * 8;
            ah[m] = *(const bf16x8*)&sAh[si];
            al[m] = *(const bf16x8*)&sAl[si];
        }
        #pragma unroll
        for (int n = 0; n < 4; ++n) {
            int col = wcol + n * 16 + l15;
            size_t off = (size_t)col * 256 + ks * 32 + l4 * 8;
            bh[n] = *(const bf16x8*)&WhTl[off];
            bl[n] = *(const bf16x8*)&WlTl[off];
        }
        #pragma unroll
        for (int m = 0; m < 4; ++m) {
            #pragma unroll
            for (int n = 0; n < 4; ++n) {
                acc[m][n] = __builtin_amdgcn_mfma_f32_16x16x32_bf16(ah[m], bh[n], acc[m][n], 0, 0, 0);
                acc[m][n] = __builtin_amdgcn_mfma_f32_16x16x32_bf16(ah[m], bl[n], acc[m][n], 0, 0, 0);
                acc[m][n] = __builtin_amdgcn_mfma_f32_16x16x32_bf16(al[m], bh[n], acc[m][n], 0, 0, 0);
            }
        }
    }
}

__device__ __forceinline__ void init_bias(f32x4 acc[4][4], const float* __restrict__ b,
                                          int wcol, int l15)
{
    #pragma unroll
    for (int n = 0; n < 4; ++n) {
        float bv = b[wcol + n * 16 + l15];
        #pragma unroll
        for (int m = 0; m < 4; ++m) {
            acc[m][n][0] = bv; acc[m][n][1] = bv; acc[m][n][2] = bv; acc[m][n][3] = bv;
        }
    }
}

// ELU + hi/lo split + swizzled store of a layer's output back into act LDS.
__device__ __forceinline__ void write_act(short* sAh, short* sAl, f32x4 acc[4][4],
                                          int l15, int l4, int wcol)
{
    #pragma unroll
    for (int m = 0; m < 4; ++m) {
        #pragma unroll
        for (int n = 0; n < 4; ++n) {
            int col = wcol + n * 16 + l15;   // next layer's k index
            int g = col >> 3;
            int k7 = col & 7;
            #pragma unroll
            for (int r = 0; r < 4; ++r) {
                int row = m * 16 + l4 * 4 + r;
                float v = elu_f(acc[m][n][r]);
                unsigned short h = bf16_rne(v);
                unsigned short l = bf16_rne(v - bf16_tof(h));
                int si = row * 256 + (g ^ (row & 15)) * 8 + k7;
                sAh[si] = (short)h;
                sAl[si] = (short)l;
            }
        }
    }
}

__global__ __launch_bounds__(256, 2) void mlp_mfma_kernel(
    const float* __restrict__ x, const float* __restrict__ dist,
    const int* __restrict__ f2ci,
    const short* __restrict__ WhT, const short* __restrict__ WlT,
    const float* __restrict__ W1,
    const float* __restrict__ b1, const float* __restrict__ b2,
    const float* __restrict__ b3,
    float* __restrict__ nodeSum)
{
    __shared__ short sAh[64 * 256];   // 32 KB
    __shared__ short sAl[64 * 256];   // 32 KB

    const int t    = threadIdx.x;
    const int lane = t & 63;
    const int wave = t >> 6;          // wave owns output cols [wave*64, wave*64+64)
    const int wcol = wave * 64;
    const int m0   = blockIdx.x * 64;
    const int l15  = lane & 15;
    const int l4   = lane >> 4;

    // ---- stage x as hi/lo bf16 into swizzled LDS ----
    #pragma unroll
    for (int r = 0; r < 16; ++r) {
        int id  = r * 256 + t;         // 0..4095
        int row = id >> 6;             // 0..63
        int kq  = id & 63;             // float4 index within row
        float4 v = *(const float4*)&x[(size_t)(m0 + row) * HID + kq * 4];
        unsigned short h0 = bf16_rne(v.x), h1 = bf16_rne(v.y),
                       h2 = bf16_rne(v.z), h3 = bf16_rne(v.w);
        unsigned short e0 = bf16_rne(v.x - bf16_tof(h0)),
                       e1 = bf16_rne(v.y - bf16_tof(h1)),
                       e2 = bf16_rne(v.z - bf16_tof(h2)),
                       e3 = bf16_rne(v.w - bf16_tof(h3));
        int gx = (kq >> 1) ^ (row & 15);
        int si = row * 256 + gx * 8 + (kq & 1) * 4;
        ushort4 hv; hv.x = h0; hv.y = h1; hv.z = h2; hv.w = h3;
        ushort4 lv; lv.x = e0; lv.y = e1; lv.z = e2; lv.w = e3;
        *(ushort4*)&sAh[si] = hv;
        *(ushort4*)&sAl[si] = lv;
    }
    __syncthreads();

    f32x4 acc[4][4];

    // ---- layer 1: elu([x,d] @ W1 + b1); distance column folded into acc init ----
    {
        float dd[4][4];
        #pragma unroll
        for (int m = 0; m < 4; ++m)
            #pragma unroll
            for (int r = 0; r < 4; ++r)
                dd[m][r] = dist[m0 + m * 16 + l4 * 4 + r];
        #pragma unroll
        for (int n = 0; n < 4; ++n) {
            int col = wcol + n * 16 + l15;
            float bv = b1[col];
            float wl = W1[(size_t)HID * HID + col];   // W1 row 256 (distance row)
            #pragma unroll
            for (int m = 0; m < 4; ++m)
                #pragma unroll
                for (int r = 0; r < 4; ++r)
                    acc[m][n][r] = fmaf(dd[m][r], wl, bv);
        }
    }
    mfma_layer(sAh, sAl, WhT, WlT, acc, l15, l4, wcol);
    __syncthreads();
    write_act(sAh, sAl, acc, l15, l4, wcol);
    __syncthreads();

    // ---- layer 2 ----
    init_bias(acc, b2, wcol, l15);
    mfma_layer(sAh, sAl, WhT + 65536, WlT + 65536, acc, l15, l4, wcol);
    __syncthreads();
    write_act(sAh, sAl, acc, l15, l4, wcol);
    __syncthreads();

    // ---- layer 3: + residual x, scatter to coarse nodes ----
    init_bias(acc, b3, wcol, l15);
    mfma_layer(sAh, sAl, WhT + 2 * 65536, WlT + 2 * 65536, acc, l15, l4, wcol);

    #pragma unroll
    for (int m = 0; m < 4; ++m) {
        #pragma unroll
        for (int r = 0; r < 4; ++r) {
            int row = m * 16 + l4 * 4 + r;
            size_t mg = (size_t)(m0 + row);
            int c = f2ci[mg];
            float* pb = nodeSum + (size_t)c * HID;
            const float* xr = x + mg * HID;
            #pragma unroll
            for (int n = 0; n < 4; ++n) {
                int col = wcol + n * 16 + l15;
                unsafeAtomicAdd(pb + col, acc[m][n][r] + xr[col]);
            }
        }
    }
}

// ---------------- fallback fp32 MLP (previous verified kernel) ----------------
__device__ __forceinline__ void gemm_layer(
    const float* __restrict__ Wg, const float* sIn, float* sW,
    float acc[4][4], int t, int mb, int n0)
{
    for (int kt = 0; kt < 16; ++kt) {
        __syncthreads();
        const float* wsrc = Wg + (size_t)kt * 16 * HID;
        #pragma unroll
        for (int r = 0; r < 4; ++r) {
            int id = r * 256 + t;
            *(float4*)&sW[id * 4] = *(const float4*)&wsrc[id * 4];
        }
        __syncthreads();
        #pragma unroll
        for (int k4 = 0; k4 < 4; ++k4) {
            int kb = kt * 16 + k4 * 4;
            float4 w[4];
            #pragma unroll
            for (int kk = 0; kk < 4; ++kk)
                w[kk] = *(const float4*)&sW[(k4 * 4 + kk) * HID + n0];
            #pragma unroll
            for (int i = 0; i < 4; ++i) {
                float4 av = *(const float4*)&sIn[(mb + i) * NPITCH + kb];
                float am[4] = {av.x, av.y, av.z, av.w};
                #pragma unroll
                for (int kk = 0; kk < 4; ++kk) {
                    acc[i][0] = fmaf(am[kk], w[kk].x, acc[i][0]);
                    acc[i][1] = fmaf(am[kk], w[kk].y, acc[i][1]);
                    acc[i][2] = fmaf(am[kk], w[kk].z, acc[i][2]);
                    acc[i][3] = fmaf(am[kk], w[kk].w, acc[i][3]);
                }
            }
        }
    }
}

__global__ __launch_bounds__(256) void mlp_kernel(
    const float* __restrict__ x, const float* __restrict__ dist,
    const int* __restrict__ f2ci,
    const float* __restrict__ W1, const float* __restrict__ b1,
    const float* __restrict__ W2, const float* __restrict__ b2,
    const float* __restrict__ W3, const float* __restrict__ b3,
    float* __restrict__ nodeSum)
{
    __shared__ float s0[16 * NPITCH];
    __shared__ float s1[16 * NPITCH];
    __shared__ float sW[16 * HID];

    const int t  = threadIdx.x;
    const int m0 = blockIdx.x * 16;
    const int n0 = (t & 63) * 4;
    const int mb = (t >> 6) * 4;

    #pragma unroll
    for (int r = 0; r < 4; ++r) {
        int id = r * 256 + t;
        int m = id >> 6, k4 = id & 63;
        *(float4*)&s0[m * NPITCH + k4 * 4] =
            *(const float4*)&x[(size_t)(m0 + m) * HID + (size_t)k4 * 4];
    }

    float acc[4][4];
    {
        float4 bv = *(const float4*)&b1[n0];
        float4 wl = *(const float4*)&W1[(size_t)HID * HID + n0];
        #pragma unroll
        for (int i = 0; i < 4; ++i) {
            float d = dist[m0 + mb + i];
            acc[i][0] = fmaf(d, wl.x, bv.x);
            acc[i][1] = fmaf(d, wl.y, bv.y);
            acc[i][2] = fmaf(d, wl.z, bv.z);
            acc[i][3] = fmaf(d, wl.w, bv.w);
        }
    }
    gemm_layer(W1, s0, sW, acc, t, mb, n0);
    #pragma unroll
    for (int i = 0; i < 4; ++i) {
        float4 v = make_float4(elu_f(acc[i][0]), elu_f(acc[i][1]),
                               elu_f(acc[i][2]), elu_f(acc[i][3]));
        *(float4*)&s1[(mb + i) * NPITCH + n0] = v;
    }
    {
        float4 bv = *(const float4*)&b2[n0];
        #pragma unroll
        for (int i = 0; i < 4; ++i) {
            acc[i][0] = bv.x; acc[i][1] = bv.y; acc[i][2] = bv.z; acc[i][3] = bv.w;
        }
    }
    gemm_layer(W2, s1, sW, acc, t, mb, n0);
    #pragma unroll
    for (int i = 0; i < 4; ++i) {
        float4 v = make_float4(elu_f(acc[i][0]), elu_f(acc[i][1]),
                               elu_f(acc[i][2]), elu_f(acc[i][3]));
        *(float4*)&s0[(mb + i) * NPITCH + n0] = v;
    }
    {
        float4 bv = *(const float4*)&b3[n0];
        #pragma unroll
        for (int i = 0; i < 4; ++i) {
            acc[i][0] = bv.x; acc[i][1] = bv.y; acc[i][2] = bv.z; acc[i][3] = bv.w;
        }
    }
    gemm_layer(W3, s0, sW, acc, t, mb, n0);
    #pragma unroll
    for (int i = 0; i < 4; ++i) {
        size_t m = (size_t)(m0 + mb + i);
        float4 xr = *(const float4*)&x[m * HID + n0];
        int c = f2ci[m];
        float* p = nodeSum + (size_t)c * HID + n0;
        unsafeAtomicAdd(p + 0, acc[i][0] + xr.x);
        unsafeAtomicAdd(p + 1, acc[i][1] + xr.y);
        unsafeAtomicAdd(p + 2, acc[i][2] + xr.z);
        unsafeAtomicAdd(p + 3, acc[i][3] + xr.w);
    }
}

// ---------------- divide node sums by counts ----------------
__global__ __launch_bounds__(256) void normalize_nodes_kernel(
    float* __restrict__ out, const int* __restrict__ nodeCnt)
{
    size_t i4 = (size_t)blockIdx.x * 256 + threadIdx.x;
    size_t f = i4 * 4;
    int cnt = nodeCnt[f >> 8];
    float s = 1.0f / (float)(cnt > 0 ? cnt : 1);
    float4 v = *(float4*)&out[f];
    v.x *= s; v.y *= s; v.z *= s; v.w *= s;
    *(float4*)&out[f] = v;
}

// ---------------- fallback: divide sums by counts (both regions) ----------------
__global__ __launch_bounds__(256) void normalize_kernel(
    float* __restrict__ out, const int* __restrict__ edgeCnt,
    const int* __restrict__ nodeCnt)
{
    size_t i4 = (size_t)blockIdx.x * 256 + threadIdx.x;
    size_t f = i4 * 4;
    int cnt;
    if (f < NODE_FLOATS) cnt = nodeCnt[f >> 8];
    else                 cnt = edgeCnt[(f - NODE_FLOATS) >> 8];
    float s = 1.0f / (float)(cnt > 0 ? cnt : 1);
    float4 v = *(float4*)&out[f];
    v.x *= s; v.y *= s; v.z *= s; v.w *= s;
    *(float4*)&out[f] = v;
}

// ---------------- coarse_edge_index passthrough (as float) ----------------
__global__ __launch_bounds__(256) void idx_copy_kernel(
    const int* __restrict__ cei, float* __restrict__ out)
{
    int i = blockIdx.x * 256 + threadIdx.x;
    out[IDX_OFF + i] = (float)cei[i];
}

extern "C" void kernel_launch(void* const* d_in, const int* in_sizes, int n_in,
                              void* d_out, int out_size, void* d_ws, size_t ws_size,
                              hipStream_t stream)
{
    const float* x    = (const float*)d_in[0];
    const float* ea   = (const float*)d_in[1];
    const float* dist = (const float*)d_in[2];
    const int*   f2ci = (const int*)d_in[3];
    const int*   f2ce = (const int*)d_in[4];
    const int*   cei  = (const int*)d_in[5];
    const float* W1   = (const float*)d_in[6];
    const float* b1   = (const float*)d_in[7];
    const float* W2   = (const float*)d_in[8];
    const float* b2   = (const float*)d_in[9];
    const float* W3   = (const float*)d_in[10];
    const float* b3   = (const float*)d_in[11];

    float* out     = (float*)d_out;
    float* nodeSum = out;                  // [65536][256]
    float* edgeSum = out + NODE_FLOATS;    // [262144][256]

    // workspace layout
    int*   edgeCnt   = (int*)d_ws;                  // 262144
    int*   nodeCnt   = edgeCnt + E_COARSE;          // 65536
    int*   edgeOff   = nodeCnt + N_COARSE;          // 262144
    int*   cursor    = edgeOff + E_COARSE;          // 262144
    int*   bucket    = cursor + E_COARSE;           // 524288
    int*   blockSums = bucket + E_FINE;             // 256
    short* WhT       = (short*)(blockSums + 256);   // 3*65536 bf16
    short* WlT       = WhT + 3 * 65536;             // 3*65536 bf16

    const size_t wsGather =
        (size_t)(E_COARSE + N_COARSE + E_COARSE + E_COARSE + E_FINE + 256) * sizeof(int);
    const size_t wsMfma = wsGather + (size_t)6 * 65536 * sizeof(short);
    const bool gatherPath = (ws_size >= wsGather);
    const bool mfmaPath   = (ws_size >= wsMfma);

    if (gatherPath) {
        hipMemsetAsync(nodeSum, 0, NODE_FLOATS * sizeof(float), stream);
        hipMemsetAsync(d_ws, 0, (size_t)(E_COARSE + N_COARSE) * sizeof(int), stream);

        if (mfmaPath)
            wsplit_kernel<<<3 * 65536 / 256, 256, 0, stream>>>(W1, W2, W3, WhT, WlT);

        counts_kernel<<<E_FINE / 256, 256, 0, stream>>>(f2ce, f2ci, edgeCnt, nodeCnt);
        scan1_kernel<<<256, 256, 0, stream>>>(edgeCnt, edgeOff, blockSums);
        scan2_kernel<<<1, 256, 0, stream>>>(blockSums);
        scan3_kernel<<<256, 256, 0, stream>>>(edgeOff, blockSums, cursor);
        fill_kernel<<<E_FINE / 256, 256, 0, stream>>>(f2ce, cursor, bucket);
        edge_gather_kernel<<<E_COARSE / 4, 256, 0, stream>>>(ea, edgeOff, edgeCnt,
                                                             bucket, edgeSum);
        if (mfmaPath)
            mlp_mfma_kernel<<<N_FINE / 64, 256, 0, stream>>>(x, dist, f2ci, WhT, WlT,
                                                             W1, b1, b2, b3, nodeSum);
        else
            mlp_kernel<<<N_FINE / 16, 256, 0, stream>>>(x, dist, f2ci,
                                                        W1, b1, W2, b2, W3, b3, nodeSum);
        normalize_nodes_kernel<<<(unsigned)(NODE_FLOATS / 4 / 256), 256, 0, stream>>>(
            out, nodeCnt);
        idx_copy_kernel<<<IDX_N / 256, 256, 0, stream>>>(cei, out);
    } else {
        hipMemsetAsync(d_out, 0, (NODE_FLOATS + EDGE_FLOATS) * sizeof(float), stream);
        hipMemsetAsync(d_ws, 0, (size_t)(E_COARSE + N_COARSE) * sizeof(int), stream);

        counts_kernel<<<E_FINE / 256, 256, 0, stream>>>(f2ce, f2ci, edgeCnt, nodeCnt);
        edge_scatter_kernel<<<E_FINE / 4, 256, 0, stream>>>(ea, f2ce, edgeSum);
        mlp_kernel<<<N_FINE / 16, 256, 0, stream>>>(x, dist, f2ci,
                                                    W1, b1, W2, b2, W3, b3, nodeSum);
        normalize_kernel<<<(unsigned)((NODE_FLOATS + EDGE_FLOATS) / 4 / 256), 256, 0, stream>>>(
            out, edgeCnt, nodeCnt);
        idx_copy_kernel<<<IDX_N / 256, 256, 0, stream>>>(cei, out);
    }
}